// Round 6
// baseline (330.952 us; speedup 1.0000x reference)
//
#include <hip/hip_runtime.h>

#define NA 50000
#define NB 20000
#define NE0 600000
#define NE1 300000
#define NE2 300000
#define DD 128

// Degree/ideg segment layout (same as the proven rdeg/ideg layout):
// [0,NA)       dout0 (src A, rel0)     [NA,2NA)      din0 (dst A, rel0)
// [2NA,3NA)    dout1 (src A, rel1)     [3NA,3NA+NB)  din1 (dst B, rel1)
// [3NA+NB,3NA+2NB) dout2 (src B, rel2) [3NA+2NB,4NA+2NB) din2 (dst A, rel2)
// Total 4NA+2NB = 240000 ints.
// rp/cursor layout: [0,NA) rel0 dst-A ; [NA,NA+NB) rel1 dst-B ; [NA+NB,2NA+NB) rel2 dst-A.

typedef short bf16x8 __attribute__((ext_vector_type(8)));
typedef float f32x4 __attribute__((ext_vector_type(4)));

__device__ __forceinline__ unsigned short f2bf(float f) {
    union { float f; unsigned int u; } v; v.f = f;
    unsigned int r = v.u + 0x7fffu + ((v.u >> 16) & 1u);   // RNE
    return (unsigned short)(r >> 16);
}
__device__ __forceinline__ float lo2f(unsigned int u) {
    union { float f; unsigned int u; } v; v.u = u << 16;
    return v.f;
}
__device__ __forceinline__ float hi2f(unsigned int u) {
    union { float f; unsigned int u; } v; v.u = u & 0xffff0000u;
    return v.f;
}

// ---- zero ideg (240000 ints = 60000 int4) -----------------------------------
__global__ __launch_bounds__(1024) void zero_k(int4* __restrict__ idegv)
{
    int i = blockIdx.x * 1024 + threadIdx.x;
    if (i < 60000) { int4 z = {0, 0, 0, 0}; idegv[i] = z; }
}

// ---- degree atomics (2 per edge, L2-resident 960KB counters) + Wt transpose -
__global__ __launch_bounds__(1024) void degwt_k(
    const int* __restrict__ s0, const int* __restrict__ d0,
    const int* __restrict__ s1, const int* __restrict__ d1,
    const int* __restrict__ s2, const int* __restrict__ d2,
    int* __restrict__ ideg,
    const float* __restrict__ W0, const float* __restrict__ W1,
    const float* __restrict__ W2, unsigned short* __restrict__ Wt)
{
    int bx = blockIdx.x;
    if (bx < 48) {   // Wt[w][c*128+k] = bf16(W_w[k*128+c])
        int i = bx * 1024 + threadIdx.x;
        int w = i >> 14, r = i & (DD * DD - 1);
        int c = r >> 7, k = r & (DD - 1);
        const float* W = (w == 0) ? W0 : ((w == 1) ? W1 : W2);
        Wt[i] = f2bf(W[k * DD + c]);
        return;
    }
    int pb = bx - 48;
    int z = (pb < 293) ? 0 : (pb < 440) ? 1 : 2;
    const int zb[3] = {0, 293, 440};
    const int En[3] = {NE0, NE1, NE2};
    const int so[3] = {0, 2 * NA, 3 * NA + NB};
    const int di[3] = {NA, 3 * NA, 3 * NA + 2 * NB};
    int E = En[z];
    const int* src = z == 0 ? s0 : z == 1 ? s1 : s2;
    const int* dst = z == 0 ? d0 : z == 1 ? d1 : d2;
    int e0 = (pb - zb[z]) * 2048 + threadIdx.x;
    #pragma unroll
    for (int j = 0; j < 2; ++j) {
        int e = e0 + j * 1024;
        if (e < E) {
            int s = src[e], d = dst[e];
            atomicAdd(&ideg[so[z] + s], 1);
            atomicAdd(&ideg[di[z] + d], 1);
        }
    }
}

// ---- rdeg (all 240K, coalesced) + 256-key chunk sums for the 3 din segs -----
__global__ __launch_bounds__(256) void rsp_k(
    const int* __restrict__ ideg, float* __restrict__ rdeg,
    int* __restrict__ spart)
{
    int y = blockIdx.y, b = blockIdx.x, t = threadIdx.x;
    if (y == 0) {
        int i = b * 256 + t;
        if (i < 4 * NA + 2 * NB) rdeg[i] = rsqrtf(fmaxf((float)ideg[i], 1.f));
        return;
    }
    __shared__ int lds[256];
    const int segb[3] = {NA, 3 * NA, 3 * NA + 2 * NB};
    const int segn[3] = {NA, NB, NA};
    int s = y - 1;
    int n = segn[s];
    if (b * 256 >= n) return;
    int key = b * 256 + t;
    lds[t] = (key < n) ? ideg[segb[s] + key] : 0;
    __syncthreads();
    for (int o = 128; o > 0; o >>= 1) {
        if (t < o) lds[t] += lds[t + o];
        __syncthreads();
    }
    if (t == 0) spart[s * 256 + b] = lds[0];
}

// ---- rowptr scan (+ cursor copy for atomic placement) -----------------------
__global__ __launch_bounds__(256) void scan3(
    const int* __restrict__ ideg, const int* __restrict__ spart,
    int* __restrict__ rp, int* __restrict__ cursor)
{
    __shared__ int lds[256];
    const int y = blockIdx.y;
    const int off[3] = {NA, 3 * NA, 3 * NA + 2 * NB};
    const int nn[3]  = {NA, NB, NA};
    const int ro[3]  = {0, NA, NA + NB};
    int n = nn[y];
    int b = blockIdx.x, t = threadIdx.x;
    if (b * 1024 >= n) return;

    // base = sum of spart chunks [0, 4b)
    lds[t] = (t < 4 * b) ? spart[y * 256 + t] : 0;
    __syncthreads();
    for (int o = 128; o > 0; o >>= 1) {
        if (t < o) lds[t] += lds[t + o];
        __syncthreads();
    }
    int pv = lds[0];
    __syncthreads();

    const int* deg = ideg + off[y];
    int base = b * 1024 + t * 4;
    int v[4]; int tsum = 0;
    #pragma unroll
    for (int k = 0; k < 4; ++k) {
        v[k] = (base + k < n) ? deg[base + k] : 0;
        tsum += v[k];
    }
    lds[t] = tsum; __syncthreads();
    for (int o = 1; o < 256; o <<= 1) {
        int x = (t >= o) ? lds[t - o] : 0;
        __syncthreads();
        lds[t] += x;
        __syncthreads();
    }
    int run = lds[t] - tsum + pv;
    int* rowptr = rp + ro[y];
    int* cur = cursor + ro[y];
    #pragma unroll
    for (int k = 0; k < 4; ++k) {
        if (base + k < n) { rowptr[base + k] = run; cur[base + k] = run; }
        run += v[k];
    }
}

// ---- fused work: MFMA GEMMs FIRST (blocks 0..547), atomic placement after ---
// GEMM-first keeps streaming/MFMA blocks resident from t=0 (R1: +4.5us).
// placement: pos = atomicAdd(&cursor[d],1)  -- 1 L2 RMW + 1 u16 store per edge
// (R1: 2 random loads + 4B store; R4 big-footprint fusion thrashed L2;
//  R5 LDS variant paid 7x edge re-reads. cursor is 480KB = L2-resident.)
// Row order within a CSR row becomes nondeterministic: sum is order-invariant.
__global__ __launch_bounds__(512) void work_kernel(
    const int* __restrict__ s0, const int* __restrict__ d0,
    const int* __restrict__ s1, const int* __restrict__ d1,
    const int* __restrict__ s2, const int* __restrict__ d2,
    int* __restrict__ cursor,
    unsigned short* __restrict__ csr0, unsigned short* __restrict__ csr1,
    unsigned short* __restrict__ csr2,
    const float* __restrict__ hA, const float* __restrict__ hB,
    const unsigned short* __restrict__ Wt, const float* __restrict__ rdeg,
    unsigned short* __restrict__ mA0, unsigned short* __restrict__ mA1,
    unsigned short* __restrict__ mB2)
{
    int bx = blockIdx.x;
    int wid  = threadIdx.x >> 6;
    int lane = threadIdx.x & 63;
    int quad = lane >> 4;
    int l16  = lane & 15;
    if (bx < 391) {   // ---- dual-W GEMM over hA ----
        int base = bx * 128 + wid * 16;
        if (base >= NA) return;
        int arow = base + l16;
        if (arow >= NA) arow = NA - 1;
        bf16x8 a[4];
        #pragma unroll
        for (int kk = 0; kk < 4; ++kk) {
            const float4* p = (const float4*)(hA + (size_t)arow * DD + kk * 32 + quad * 8);
            float4 u = p[0], w = p[1];
            bf16x8 t;
            t[0] = (short)f2bf(u.x); t[1] = (short)f2bf(u.y);
            t[2] = (short)f2bf(u.z); t[3] = (short)f2bf(u.w);
            t[4] = (short)f2bf(w.x); t[5] = (short)f2bf(w.y);
            t[6] = (short)f2bf(w.z); t[7] = (short)f2bf(w.w);
            a[kk] = t;
        }
        float rs0[4], rs1[4]; int orow0 = base + quad * 4;
        #pragma unroll
        for (int r = 0; r < 4; ++r) {
            int orow = orow0 + r; int c = orow < NA ? orow : 0;
            rs0[r] = rdeg[c]; rs1[r] = rdeg[2 * NA + c];
        }
        #pragma unroll
        for (int ct = 0; ct < 8; ++ct) {
            f32x4 acc0 = {0.f, 0.f, 0.f, 0.f};
            f32x4 acc1 = {0.f, 0.f, 0.f, 0.f};
            const unsigned short* wp = Wt + (size_t)(ct * 16 + l16) * DD + quad * 8;
            #pragma unroll
            for (int kk = 0; kk < 4; ++kk) {
                bf16x8 b0 = *(const bf16x8*)(wp + kk * 32);
                bf16x8 b1 = *(const bf16x8*)(wp + 16384 + kk * 32);
                acc0 = __builtin_amdgcn_mfma_f32_16x16x32_bf16(a[kk], b0, acc0, 0, 0, 0);
                acc1 = __builtin_amdgcn_mfma_f32_16x16x32_bf16(a[kk], b1, acc1, 0, 0, 0);
            }
            #pragma unroll
            for (int r = 0; r < 4; ++r) {
                int orow = orow0 + r;
                if (orow < NA) {
                    mA0[(size_t)orow * DD + ct * 16 + l16] = f2bf(acc0[r] * rs0[r]);
                    mA1[(size_t)orow * DD + ct * 16 + l16] = f2bf(acc1[r] * rs1[r]);
                }
            }
        }
        return;
    }
    if (bx < 548) {   // ---- W2 GEMM over hB ----
        int base = (bx - 391) * 128 + wid * 16;
        if (base >= NB) return;
        int arow = base + l16;
        if (arow >= NB) arow = NB - 1;
        bf16x8 a[4];
        #pragma unroll
        for (int kk = 0; kk < 4; ++kk) {
            const float4* p = (const float4*)(hB + (size_t)arow * DD + kk * 32 + quad * 8);
            float4 u = p[0], w = p[1];
            bf16x8 t;
            t[0] = (short)f2bf(u.x); t[1] = (short)f2bf(u.y);
            t[2] = (short)f2bf(u.z); t[3] = (short)f2bf(u.w);
            t[4] = (short)f2bf(w.x); t[5] = (short)f2bf(w.y);
            t[6] = (short)f2bf(w.z); t[7] = (short)f2bf(w.w);
            a[kk] = t;
        }
        float rs[4]; int orow0 = base + quad * 4;
        #pragma unroll
        for (int r = 0; r < 4; ++r) {
            int orow = orow0 + r;
            rs[r] = rdeg[3 * NA + NB + (orow < NB ? orow : 0)];
        }
        #pragma unroll
        for (int ct = 0; ct < 8; ++ct) {
            f32x4 acc = {0.f, 0.f, 0.f, 0.f};
            const unsigned short* wp = Wt + 32768 + (size_t)(ct * 16 + l16) * DD + quad * 8;
            #pragma unroll
            for (int kk = 0; kk < 4; ++kk) {
                bf16x8 b = *(const bf16x8*)(wp + kk * 32);
                acc = __builtin_amdgcn_mfma_f32_16x16x32_bf16(a[kk], b, acc, 0, 0, 0);
            }
            #pragma unroll
            for (int r = 0; r < 4; ++r) {
                int orow = orow0 + r;
                if (orow < NB)
                    mB2[(size_t)orow * DD + ct * 16 + l16] = f2bf(acc[r] * rs[r]);
            }
        }
        return;
    }
    // ---- placement: 1172 blocks x 1024 edges (2 per thread, independent) ----
    int pb = bx - 548;
    int z = (pb < 586) ? 0 : (pb < 879) ? 1 : 2;
    const int zb[3] = {0, 586, 879};
    const int En[3] = {NE0, NE1, NE2};
    const int ro[3] = {0, NA, NA + NB};
    int E = En[z];
    const int* src = z == 0 ? s0 : z == 1 ? s1 : s2;
    const int* dst = z == 0 ? d0 : z == 1 ? d1 : d2;
    unsigned short* csr = z == 0 ? csr0 : z == 1 ? csr1 : csr2;
    int* cur = cursor + ro[z];
    int e0 = (pb - zb[z]) * 1024 + threadIdx.x;
    int e1 = e0 + 512;
    bool v0 = e0 < E, v1 = e1 < E;
    int ce0 = v0 ? e0 : 0, ce1 = v1 ? e1 : 0;
    int d_0 = dst[ce0];
    int d_1 = dst[ce1];
    int s_0 = src[ce0];
    int s_1 = src[ce1];
    int p0 = 0, p1 = 0;
    if (v0) p0 = atomicAdd(&cur[d_0], 1);   // guarded: must not bump counters
    if (v1) p1 = atomicAdd(&cur[d_1], 1);
    if (v0) csr[p0] = (unsigned short)s_0;
    if (v1) csr[p1] = (unsigned short)s_1;
}

// ---- gather: uint4 loads, 16 lanes/row -> 4 edges per wave instruction ------
__device__ __forceinline__ void acc8(float* o, uint4 u) {
    o[0] += lo2f(u.x); o[1] += hi2f(u.x);
    o[2] += lo2f(u.y); o[3] += hi2f(u.y);
    o[4] += lo2f(u.z); o[5] += hi2f(u.z);
    o[6] += lo2f(u.w); o[7] += hi2f(u.w);
}
__device__ __forceinline__ void gather_rel4(
    const char* __restrict__ Mb, const unsigned short* __restrict__ csr,
    int st, int n, int lane, int q, unsigned laneoff, float* o)
{
    for (int ch = 0; ch < n; ch += 64) {
        int m = n - ch; if (m > 64) m = 64;
        int idx = csr[st + ch + (lane < m ? lane : m - 1)];  // coalesced prefetch
        int j = 0;
        for (; j + 8 <= m; j += 8) {        // 2 loads in flight, 8 edges/iter
            int sA = __shfl(idx, j + q);
            int sB = __shfl(idx, j + 4 + q);
            uint4 uA = *(const uint4*)(Mb + (((unsigned)sA << 8) + laneoff));
            uint4 uB = *(const uint4*)(Mb + (((unsigned)sB << 8) + laneoff));
            acc8(o, uA); acc8(o, uB);
        }
        if (j + 4 <= m) {
            int s = __shfl(idx, j + q);
            uint4 u = *(const uint4*)(Mb + (((unsigned)s << 8) + laneoff));
            acc8(o, u);
            j += 4;
        }
        if (j < m) {                        // masked tail group
            int jj = j + q;
            float w = jj < m ? 1.f : 0.f;
            int s = __shfl(idx, jj < m ? jj : m - 1);
            uint4 u = *(const uint4*)(Mb + (((unsigned)s << 8) + laneoff));
            o[0] = fmaf(w, lo2f(u.x), o[0]); o[1] = fmaf(w, hi2f(u.x), o[1]);
            o[2] = fmaf(w, lo2f(u.y), o[2]); o[3] = fmaf(w, hi2f(u.y), o[3]);
            o[4] = fmaf(w, lo2f(u.z), o[4]); o[5] = fmaf(w, hi2f(u.z), o[5]);
            o[6] = fmaf(w, lo2f(u.w), o[6]); o[7] = fmaf(w, hi2f(u.w), o[7]);
        }
    }
}

// ---- fused gather: blocks [0,12500) -> out_A rows; [12500,17500) -> out_B ---
__global__ __launch_bounds__(256) void gather_all(
    const unsigned short* __restrict__ mA0, const unsigned short* __restrict__ mA1,
    const unsigned short* __restrict__ mB2,
    const unsigned short* __restrict__ csr0, const unsigned short* __restrict__ csr1,
    const unsigned short* __restrict__ csr2,
    const int* __restrict__ rp, const int* __restrict__ ideg,
    const float* __restrict__ rdeg,
    const float* __restrict__ b0, const float* __restrict__ b1,
    const float* __restrict__ b2,
    float* __restrict__ out)
{
    int wid = threadIdx.x >> 6, lane = threadIdx.x & 63;
    int q = lane >> 4, l16 = lane & 15;
    unsigned laneoff = (unsigned)l16 * 16u;
    float v[8];
    #pragma unroll
    for (int i = 0; i < 8; ++i) v[i] = 0.f;
    float* op;
    const float *bia, *bib;

    if (blockIdx.x < 12500) {
        int d = blockIdx.x * 4 + wid;   // always < NA
        float c[8];
        #pragma unroll
        for (int i = 0; i < 8; ++i) c[i] = 0.f;
        gather_rel4((const char*)mA0, csr0, rp[d], ideg[NA + d], lane, q, laneoff, v);
        gather_rel4((const char*)mB2, csr2, rp[NA + NB + d], ideg[3 * NA + 2 * NB + d],
                    lane, q, laneoff, c);
        float r0 = rdeg[NA + d], r2 = rdeg[3 * NA + 2 * NB + d];
        #pragma unroll
        for (int i = 0; i < 8; ++i) v[i] = v[i] * r0 + c[i] * r2;
        op = out + (size_t)d * DD;
        bia = b0; bib = b2;
    } else {
        int d = (blockIdx.x - 12500) * 4 + wid;   // always < NB
        gather_rel4((const char*)mA1, csr1, rp[NA + d], ideg[3 * NA + d],
                    lane, q, laneoff, v);
        float r1 = rdeg[3 * NA + d];
        #pragma unroll
        for (int i = 0; i < 8; ++i) v[i] *= r1;
        op = out + (size_t)(NA + d) * DD;
        bia = b1; bib = 0;
    }

    #pragma unroll
    for (int i = 0; i < 8; ++i) {
        v[i] += __shfl_down(v[i], 32);
        v[i] += __shfl_down(v[i], 16);
    }
    if (lane < 16) {
        int col = l16 * 8;
        float4 ba0 = *(const float4*)(bia + col);
        float4 ba1 = *(const float4*)(bia + col + 4);
        if (bib) {
            float4 bb0 = *(const float4*)(bib + col);
            float4 bb1 = *(const float4*)(bib + col + 4);
            ba0.x += bb0.x; ba0.y += bb0.y; ba0.z += bb0.z; ba0.w += bb0.w;
            ba1.x += bb1.x; ba1.y += bb1.y; ba1.z += bb1.z; ba1.w += bb1.w;
        }
        float4 o0 = {v[0] + ba0.x, v[1] + ba0.y, v[2] + ba0.z, v[3] + ba0.w};
        float4 o1 = {v[4] + ba1.x, v[5] + ba1.y, v[6] + ba1.z, v[7] + ba1.w};
        *(float4*)(op + col) = o0;
        *(float4*)(op + col + 4) = o1;
    }
}

extern "C" void kernel_launch(void* const* d_in, const int* in_sizes, int n_in,
                              void* d_out, int out_size, void* d_ws, size_t ws_size,
                              hipStream_t stream) {
    const float* hA = (const float*)d_in[0];
    const float* hB = (const float*)d_in[1];
    const float* W0 = (const float*)d_in[2];
    const float* b0 = (const float*)d_in[3];
    const float* W1 = (const float*)d_in[4];
    const float* b1 = (const float*)d_in[5];
    const float* W2 = (const float*)d_in[6];
    const float* b2 = (const float*)d_in[7];
    const int* s0 = (const int*)d_in[8];
    const int* d0 = (const int*)d_in[9];
    const int* s1 = (const int*)d_in[10];
    const int* d1 = (const int*)d_in[11];
    const int* s2 = (const int*)d_in[12];
    const int* d2 = (const int*)d_in[13];
    float* out = (float*)d_out;
    char* ws = (char*)d_ws;

    // ws layout (proven offsets; histogram buffers deleted, cursor in cum8's
    // slot). No aliasing anywhere now: P16/cum8/rank are gone.
    unsigned short* mA0 = (unsigned short*)(ws + 0);          // 12.8 MB
    unsigned short* mA1 = (unsigned short*)(ws + 12800000);   // 12.8 MB
    unsigned short* mB2 = (unsigned short*)(ws + 25600000);   // 5.12 MB
    unsigned short* Wt  = (unsigned short*)(ws + 30720000);   // 96 KB
    float* rdeg         = (float*)(ws + 30818304);            // 960 KB
    int*   ideg         = (int*)  (ws + 31778304);            // 960 KB (16B aligned)
    int*   rp           = (int*)  (ws + 32738304);            // 480 KB
    int*   spart        = (int*)  (ws + 33218304);            // 3 KB
    int*   cursor       = (int*)  (ws + 33221376);            // 480 KB
    unsigned short* csr0= (unsigned short*)(ws + 35941376);   // 1.2 MB (u16)
    unsigned short* csr1= (unsigned short*)(ws + 37141376);   // 0.6 MB (u16)
    unsigned short* csr2= (unsigned short*)(ws + 37741376);   // 0.6 MB (u16)

    zero_k<<<59, 1024, 0, stream>>>((int4*)ideg);
    degwt_k<<<48 + 293 + 147 + 147, 1024, 0, stream>>>(s0, d0, s1, d1, s2, d2,
        ideg, W0, W1, W2, Wt);
    rsp_k<<<dim3(938, 4), 256, 0, stream>>>(ideg, rdeg, spart);
    scan3<<<dim3(49, 3), 256, 0, stream>>>(ideg, spart, rp, cursor);
    work_kernel<<<548 + 1172, 512, 0, stream>>>(s0, d0, s1, d1, s2, d2,
        cursor, csr0, csr1, csr2,
        hA, hB, Wt, rdeg, mA0, mA1, mB2);
    gather_all<<<12500 + 5000, 256, 0, stream>>>(mA0, mA1, mB2,
        csr0, csr1, csr2, rp, ideg, rdeg, b0, b1, b2, out);
}

// Round 7
// 239.508 us; speedup vs baseline: 1.3818x; 1.3818x over previous
//
#include <hip/hip_runtime.h>

#define NA 50000
#define NB 20000
#define NE0 600000
#define NE1 300000
#define NE2 300000
#define DD 128
#define SUB 32768     // keys per LDS histogram pass (16-bit packed counters, 64 KB)
#define PER 18750     // edges per group: NE0/32 = NE1/16 = NE2/16

// P packed-ushort cell layout (cell = Po[cfg] + g*K + k):
// cfg0 dout0 G=32,K=NA @0        ; cfg1 din0 G=32,K=NA @1600000
// cfg2 dout1 G=16,K=NA @3200000  ; cfg3 din1 G=16,K=NB @4000000
// cfg4 dout2 G=16,K=NB @4320000  ; cfg5 din2 G=16,K=NA @4640000
// CUM8 uchar layout: C0 @0 (32*NA) ; C1 @1600000 (16*NB) ; C2 @1920000 (16*NA)

typedef short bf16x8 __attribute__((ext_vector_type(8)));
typedef float f32x4 __attribute__((ext_vector_type(4)));

__device__ __forceinline__ unsigned short f2bf(float f) {
    union { float f; unsigned int u; } v; v.f = f;
    unsigned int r = v.u + 0x7fffu + ((v.u >> 16) & 1u);   // RNE
    return (unsigned short)(r >> 16);
}
__device__ __forceinline__ float lo2f(unsigned int u) {
    union { float f; unsigned int u; } v; v.u = u << 16;
    return v.f;
}
__device__ __forceinline__ float hi2f(unsigned int u) {
    union { float f; unsigned int u; } v; v.u = u & 0xffff0000u;
    return v.f;
}

// ---- LDS histograms (z=0..5) + W->bf16 W^T transpose (z=6) ------------------
__global__ __launch_bounds__(1024) void hist_kernel(
    const int* __restrict__ s0, const int* __restrict__ d0,
    const int* __restrict__ s1, const int* __restrict__ d1,
    const int* __restrict__ s2, const int* __restrict__ d2,
    unsigned int* __restrict__ Pd,
    unsigned char* __restrict__ rank0, unsigned char* __restrict__ rank1,
    unsigned char* __restrict__ rank2,
    const float* __restrict__ W0, const float* __restrict__ W1,
    const float* __restrict__ W2, unsigned short* __restrict__ Wt)
{
    __shared__ unsigned int h32[SUB / 2];
    const int cfg = blockIdx.z;
    if (cfg == 6) {   // Wt[w][c*128+k] = bf16(W_w[k*128+c])
        int flat = blockIdx.y * 2 + blockIdx.x;
        if (flat >= 48) return;
        int i = flat * 1024 + threadIdx.x;
        int w = i >> 14, r = i & (DD * DD - 1);
        int c = r >> 7, k = r & (DD - 1);
        const float* W = (w == 0) ? W0 : ((w == 1) ? W1 : W2);
        Wt[i] = f2bf(W[k * DD + c]);
        return;
    }
    const int En[6] = {NE0, NE0, NE1, NE1, NE2, NE2};
    const int Kn[6] = {NA, NA, NA, NB, NB, NA};
    const int Gn[6] = {32, 32, 16, 16, 16, 16};
    const int Po[6] = {0, 1600000, 3200000, 4000000, 4320000, 4640000};
    int E = En[cfg], K = Kn[cfg], G = Gn[cfg];
    int sub = blockIdx.x, g = blockIdx.y;
    int nsub = (K + SUB - 1) / SUB;
    if (sub >= nsub || g >= G) return;
    const int* keys = cfg == 0 ? s0 : cfg == 1 ? d0 : cfg == 2 ? s1
                    : cfg == 3 ? d1 : cfg == 4 ? s2 : d2;
    unsigned char* rk = cfg == 1 ? rank0 : cfg == 3 ? rank1
                      : cfg == 5 ? rank2 : (unsigned char*)0;
    int lo = sub * SUB;
    int hi = min(K, lo + SUB);
    int cnt = hi - lo;
    for (int i = threadIdx.x; i < SUB / 2; i += 1024) h32[i] = 0;
    __syncthreads();
    int e1 = min(E, g * PER + PER);
    for (int e = g * PER + threadIdx.x; e < e1; e += 1024) {
        int k = keys[e];
        if (k >= lo && k < hi) {
            int kk = k - lo;
            unsigned sh = (kk & 1) << 4;
            unsigned old = atomicAdd(&h32[kk >> 1], 1u << sh);
            if (rk) rk[e] = (unsigned char)((old >> sh) & 0xffu);
        }
    }
    __syncthreads();
    unsigned int* outp = Pd + ((Po[cfg] + g * K + lo) >> 1);
    for (int i = threadIdx.x; i < cnt / 2; i += 1024) outp[i] = h32[i];
}

// ---- fused: partial sums -> ideg/rdeg; din cfgs also emit CUM8 + spart ------
// 1 key per thread, fully coalesced. spart granularity: 256-key chunks.
__global__ __launch_bounds__(256) void reduce2(
    const unsigned short* __restrict__ P16, int* __restrict__ ideg,
    float* __restrict__ rdeg, int* __restrict__ spart,
    unsigned char* __restrict__ cum8)
{
    __shared__ int lds[256];
    const int y = blockIdx.y;
    const int Ro[6] = {0, NA, 2 * NA, 3 * NA, 3 * NA + NB, 3 * NA + 2 * NB};
    const int Kr[6] = {NA, NA, NA, NB, NB, NA};
    const int Gr[6] = {32, 32, 16, 16, 16, 16};
    const int Po[6] = {0, 1600000, 3200000, 4000000, 4320000, 4640000};
    const int Co[6] = {0, 0, 0, 1600000, 0, 1920000};
    int K = Kr[y], G = Gr[y];
    int b = blockIdx.x, t = threadIdx.x;
    int nchunk = (K + 255) >> 8;
    if (b >= nchunk) return;
    int key = b * 256 + t;
    bool valid = key < K;
    bool din = (y == 1) || (y == 3) || (y == 5);
    const unsigned short* p = P16 + Po[y] + key;
    unsigned char* cb = cum8 + Co[y] + key;
    int run = 0;
    for (int g = 0; g < G; ++g) {
        if (din && valid) cb[g * K] = (unsigned char)run;
        run += valid ? p[g * K] : 0;
    }
    if (valid) {
        ideg[Ro[y] + key] = run;
        rdeg[Ro[y] + key] = rsqrtf(fmaxf((float)run, 1.f));
    }
    if (din) {
        int slot = (y - 1) >> 1;
        lds[t] = run; __syncthreads();
        for (int o = 128; o > 0; o >>= 1) {
            if (t < o) lds[t] += lds[t + o];
            __syncthreads();
        }
        if (t == 0) spart[slot * 256 + b] = lds[0];
    }
}

// ---- rowptr scan: spine over 256-key spart chunks + block-local scan --------
__global__ __launch_bounds__(256) void scan3(
    const int* __restrict__ ideg, const int* __restrict__ spart,
    int* __restrict__ rp)
{
    __shared__ int lds[256];
    const int y = blockIdx.y;
    const int off[3] = {NA, 3 * NA, 3 * NA + 2 * NB};
    const int nn[3]  = {NA, NB, NA};
    const int ro[3]  = {0, NA, NA + NB};
    int n = nn[y];
    int b = blockIdx.x, t = threadIdx.x;
    if (b * 1024 >= n) return;

    // base = sum of spart chunks [0, 4b)
    lds[t] = (t < 4 * b) ? spart[y * 256 + t] : 0;
    __syncthreads();
    for (int o = 128; o > 0; o >>= 1) {
        if (t < o) lds[t] += lds[t + o];
        __syncthreads();
    }
    int pv = lds[0];
    __syncthreads();

    const int* deg = ideg + off[y];
    int base = b * 1024 + t * 4;
    int v[4]; int tsum = 0;
    #pragma unroll
    for (int k = 0; k < 4; ++k) {
        v[k] = (base + k < n) ? deg[base + k] : 0;
        tsum += v[k];
    }
    lds[t] = tsum; __syncthreads();
    for (int o = 1; o < 256; o <<= 1) {
        int x = (t >= o) ? lds[t - o] : 0;
        __syncthreads();
        lds[t] += x;
        __syncthreads();
    }
    int run = lds[t] - tsum + pv;
    int* rowptr = rp + ro[y];
    #pragma unroll
    for (int k = 0; k < 4; ++k) {
        if (base + k < n) rowptr[base + k] = run;
        run += v[k];
    }
}

// ---- fused work: MFMA GEMMs FIRST (blocks 0..547), placement after ----------
// GEMM-first keeps streaming/MFMA blocks resident from t=0 (R1: +4.5us).
// placement (R1 addressing, proven): pos = rp[d] + cum8[g*K+d] + rank8[e].
// rp (480KB) and cum8 (2.7MB) are L2-resident (R4's 10.9MB pos32 thrashed).
// This round: 4 independent edges/thread (8 random loads in flight) + u16 csr
// stores (halves scatter churn; u16 proven correct in R4/R5).
__global__ __launch_bounds__(512) void work_kernel(
    const int* __restrict__ s0, const int* __restrict__ d0,
    const int* __restrict__ s1, const int* __restrict__ d1,
    const int* __restrict__ s2, const int* __restrict__ d2,
    const unsigned char* __restrict__ cum8,
    const unsigned char* __restrict__ rank0, const unsigned char* __restrict__ rank1,
    const unsigned char* __restrict__ rank2,
    const int* __restrict__ rp,
    unsigned short* __restrict__ csr0, unsigned short* __restrict__ csr1,
    unsigned short* __restrict__ csr2,
    const float* __restrict__ hA, const float* __restrict__ hB,
    const unsigned short* __restrict__ Wt, const float* __restrict__ rdeg,
    unsigned short* __restrict__ mA0, unsigned short* __restrict__ mA1,
    unsigned short* __restrict__ mB2)
{
    int bx = blockIdx.x;
    int wid  = threadIdx.x >> 6;
    int lane = threadIdx.x & 63;
    int quad = lane >> 4;
    int l16  = lane & 15;
    if (bx < 391) {   // ---- dual-W GEMM over hA ----
        int base = bx * 128 + wid * 16;
        if (base >= NA) return;
        int arow = base + l16;
        if (arow >= NA) arow = NA - 1;
        bf16x8 a[4];
        #pragma unroll
        for (int kk = 0; kk < 4; ++kk) {
            const float4* p = (const float4*)(hA + (size_t)arow * DD + kk * 32 + quad * 8);
            float4 u = p[0], w = p[1];
            bf16x8 t;
            t[0] = (short)f2bf(u.x); t[1] = (short)f2bf(u.y);
            t[2] = (short)f2bf(u.z); t[3] = (short)f2bf(u.w);
            t[4] = (short)f2bf(w.x); t[5] = (short)f2bf(w.y);
            t[6] = (short)f2bf(w.z); t[7] = (short)f2bf(w.w);
            a[kk] = t;
        }
        float rs0[4], rs1[4]; int orow0 = base + quad * 4;
        #pragma unroll
        for (int r = 0; r < 4; ++r) {
            int orow = orow0 + r; int c = orow < NA ? orow : 0;
            rs0[r] = rdeg[c]; rs1[r] = rdeg[2 * NA + c];
        }
        #pragma unroll
        for (int ct = 0; ct < 8; ++ct) {
            f32x4 acc0 = {0.f, 0.f, 0.f, 0.f};
            f32x4 acc1 = {0.f, 0.f, 0.f, 0.f};
            const unsigned short* wp = Wt + (size_t)(ct * 16 + l16) * DD + quad * 8;
            #pragma unroll
            for (int kk = 0; kk < 4; ++kk) {
                bf16x8 b0 = *(const bf16x8*)(wp + kk * 32);
                bf16x8 b1 = *(const bf16x8*)(wp + 16384 + kk * 32);
                acc0 = __builtin_amdgcn_mfma_f32_16x16x32_bf16(a[kk], b0, acc0, 0, 0, 0);
                acc1 = __builtin_amdgcn_mfma_f32_16x16x32_bf16(a[kk], b1, acc1, 0, 0, 0);
            }
            #pragma unroll
            for (int r = 0; r < 4; ++r) {
                int orow = orow0 + r;
                if (orow < NA) {
                    mA0[(size_t)orow * DD + ct * 16 + l16] = f2bf(acc0[r] * rs0[r]);
                    mA1[(size_t)orow * DD + ct * 16 + l16] = f2bf(acc1[r] * rs1[r]);
                }
            }
        }
        return;
    }
    if (bx < 548) {   // ---- W2 GEMM over hB ----
        int base = (bx - 391) * 128 + wid * 16;
        if (base >= NB) return;
        int arow = base + l16;
        if (arow >= NB) arow = NB - 1;
        bf16x8 a[4];
        #pragma unroll
        for (int kk = 0; kk < 4; ++kk) {
            const float4* p = (const float4*)(hB + (size_t)arow * DD + kk * 32 + quad * 8);
            float4 u = p[0], w = p[1];
            bf16x8 t;
            t[0] = (short)f2bf(u.x); t[1] = (short)f2bf(u.y);
            t[2] = (short)f2bf(u.z); t[3] = (short)f2bf(u.w);
            t[4] = (short)f2bf(w.x); t[5] = (short)f2bf(w.y);
            t[6] = (short)f2bf(w.z); t[7] = (short)f2bf(w.w);
            a[kk] = t;
        }
        float rs[4]; int orow0 = base + quad * 4;
        #pragma unroll
        for (int r = 0; r < 4; ++r) {
            int orow = orow0 + r;
            rs[r] = rdeg[3 * NA + NB + (orow < NB ? orow : 0)];
        }
        #pragma unroll
        for (int ct = 0; ct < 8; ++ct) {
            f32x4 acc = {0.f, 0.f, 0.f, 0.f};
            const unsigned short* wp = Wt + 32768 + (size_t)(ct * 16 + l16) * DD + quad * 8;
            #pragma unroll
            for (int kk = 0; kk < 4; ++kk) {
                bf16x8 b = *(const bf16x8*)(wp + kk * 32);
                acc = __builtin_amdgcn_mfma_f32_16x16x32_bf16(a[kk], b, acc, 0, 0, 0);
            }
            #pragma unroll
            for (int r = 0; r < 4; ++r) {
                int orow = orow0 + r;
                if (orow < NB)
                    mB2[(size_t)orow * DD + ct * 16 + l16] = f2bf(acc[r] * rs[r]);
            }
        }
        return;
    }
    // ---- placement: 587 blocks x 2048 edges (4 per thread, independent) ----
    int pb = bx - 548;
    int z = (pb < 293) ? 0 : (pb < 440) ? 1 : 2;
    const int zb[3] = {0, 293, 440};
    const int En[3] = {NE0, NE1, NE2};
    const int Kn[3] = {NA, NB, NA};
    const int Co[3] = {0, 1600000, 1920000};
    const int ro[3] = {0, NA, NA + NB};
    int E = En[z], K = Kn[z];
    const int* src = z == 0 ? s0 : z == 1 ? s1 : s2;
    const int* dst = z == 0 ? d0 : z == 1 ? d1 : d2;
    const unsigned char* rk = z == 0 ? rank0 : z == 1 ? rank1 : rank2;
    unsigned short* csr = z == 0 ? csr0 : z == 1 ? csr1 : csr2;
    int ebase = (pb - zb[z]) * 2048 + threadIdx.x;
    int ce[4]; bool vv[4];
    #pragma unroll
    for (int j = 0; j < 4; ++j) {
        int e = ebase + j * 512;
        vv[j] = e < E;
        ce[j] = vv[j] ? e : 0;
    }
    int dd_[4], rr[4], ss[4];
    #pragma unroll
    for (int j = 0; j < 4; ++j) dd_[j] = dst[ce[j]];   // coalesced
    #pragma unroll
    for (int j = 0; j < 4; ++j) rr[j] = rk[ce[j]];     // coalesced
    #pragma unroll
    for (int j = 0; j < 4; ++j) ss[j] = src[ce[j]];    // coalesced
    int pp[4];
    #pragma unroll
    for (int j = 0; j < 4; ++j) {       // 8 independent random loads in flight
        int g = ce[j] / PER;
        pp[j] = rp[ro[z] + dd_[j]] + (int)cum8[Co[z] + g * K + dd_[j]] + rr[j];
    }
    #pragma unroll
    for (int j = 0; j < 4; ++j)
        if (vv[j]) csr[pp[j]] = (unsigned short)ss[j];
}

// ---- gather: uint4 loads, 16 lanes/row -> 4 edges per wave instruction ------
__device__ __forceinline__ void acc8(float* o, uint4 u) {
    o[0] += lo2f(u.x); o[1] += hi2f(u.x);
    o[2] += lo2f(u.y); o[3] += hi2f(u.y);
    o[4] += lo2f(u.z); o[5] += hi2f(u.z);
    o[6] += lo2f(u.w); o[7] += hi2f(u.w);
}
__device__ __forceinline__ void gather_rel4(
    const char* __restrict__ Mb, const unsigned short* __restrict__ csr,
    int st, int n, int lane, int q, unsigned laneoff, float* o)
{
    for (int ch = 0; ch < n; ch += 64) {
        int m = n - ch; if (m > 64) m = 64;
        int idx = csr[st + ch + (lane < m ? lane : m - 1)];  // coalesced prefetch
        int j = 0;
        for (; j + 8 <= m; j += 8) {        // 2 loads in flight, 8 edges/iter
            int sA = __shfl(idx, j + q);
            int sB = __shfl(idx, j + 4 + q);
            uint4 uA = *(const uint4*)(Mb + (((unsigned)sA << 8) + laneoff));
            uint4 uB = *(const uint4*)(Mb + (((unsigned)sB << 8) + laneoff));
            acc8(o, uA); acc8(o, uB);
        }
        if (j + 4 <= m) {
            int s = __shfl(idx, j + q);
            uint4 u = *(const uint4*)(Mb + (((unsigned)s << 8) + laneoff));
            acc8(o, u);
            j += 4;
        }
        if (j < m) {                        // masked tail group
            int jj = j + q;
            float w = jj < m ? 1.f : 0.f;
            int s = __shfl(idx, jj < m ? jj : m - 1);
            uint4 u = *(const uint4*)(Mb + (((unsigned)s << 8) + laneoff));
            o[0] = fmaf(w, lo2f(u.x), o[0]); o[1] = fmaf(w, hi2f(u.x), o[1]);
            o[2] = fmaf(w, lo2f(u.y), o[2]); o[3] = fmaf(w, hi2f(u.y), o[3]);
            o[4] = fmaf(w, lo2f(u.z), o[4]); o[5] = fmaf(w, hi2f(u.z), o[5]);
            o[6] = fmaf(w, lo2f(u.w), o[6]); o[7] = fmaf(w, hi2f(u.w), o[7]);
        }
    }
}

// ---- fused gather: blocks [0,12500) -> out_A rows; [12500,17500) -> out_B ---
__global__ __launch_bounds__(256) void gather_all(
    const unsigned short* __restrict__ mA0, const unsigned short* __restrict__ mA1,
    const unsigned short* __restrict__ mB2,
    const unsigned short* __restrict__ csr0, const unsigned short* __restrict__ csr1,
    const unsigned short* __restrict__ csr2,
    const int* __restrict__ rp, const int* __restrict__ ideg,
    const float* __restrict__ rdeg,
    const float* __restrict__ b0, const float* __restrict__ b1,
    const float* __restrict__ b2,
    float* __restrict__ out)
{
    int wid = threadIdx.x >> 6, lane = threadIdx.x & 63;
    int q = lane >> 4, l16 = lane & 15;
    unsigned laneoff = (unsigned)l16 * 16u;
    float v[8];
    #pragma unroll
    for (int i = 0; i < 8; ++i) v[i] = 0.f;
    float* op;
    const float *bia, *bib;

    if (blockIdx.x < 12500) {
        int d = blockIdx.x * 4 + wid;   // always < NA
        float c[8];
        #pragma unroll
        for (int i = 0; i < 8; ++i) c[i] = 0.f;
        gather_rel4((const char*)mA0, csr0, rp[d], ideg[NA + d], lane, q, laneoff, v);
        gather_rel4((const char*)mB2, csr2, rp[NA + NB + d], ideg[3 * NA + 2 * NB + d],
                    lane, q, laneoff, c);
        float r0 = rdeg[NA + d], r2 = rdeg[3 * NA + 2 * NB + d];
        #pragma unroll
        for (int i = 0; i < 8; ++i) v[i] = v[i] * r0 + c[i] * r2;
        op = out + (size_t)d * DD;
        bia = b0; bib = b2;
    } else {
        int d = (blockIdx.x - 12500) * 4 + wid;   // always < NB
        gather_rel4((const char*)mA1, csr1, rp[NA + d], ideg[3 * NA + d],
                    lane, q, laneoff, v);
        float r1 = rdeg[3 * NA + d];
        #pragma unroll
        for (int i = 0; i < 8; ++i) v[i] *= r1;
        op = out + (size_t)(NA + d) * DD;
        bia = b1; bib = 0;
    }

    #pragma unroll
    for (int i = 0; i < 8; ++i) {
        v[i] += __shfl_down(v[i], 32);
        v[i] += __shfl_down(v[i], 16);
    }
    if (lane < 16) {
        int col = l16 * 8;
        float4 ba0 = *(const float4*)(bia + col);
        float4 ba1 = *(const float4*)(bia + col + 4);
        if (bib) {
            float4 bb0 = *(const float4*)(bib + col);
            float4 bb1 = *(const float4*)(bib + col + 4);
            ba0.x += bb0.x; ba0.y += bb0.y; ba0.z += bb0.z; ba0.w += bb0.w;
            ba1.x += bb1.x; ba1.y += bb1.y; ba1.z += bb1.z; ba1.w += bb1.w;
        }
        float4 o0 = {v[0] + ba0.x, v[1] + ba0.y, v[2] + ba0.z, v[3] + ba0.w};
        float4 o1 = {v[4] + ba1.x, v[5] + ba1.y, v[6] + ba1.z, v[7] + ba1.w};
        *(float4*)(op + col) = o0;
        *(float4*)(op + col + 4) = o1;
    }
}

extern "C" void kernel_launch(void* const* d_in, const int* in_sizes, int n_in,
                              void* d_out, int out_size, void* d_ws, size_t ws_size,
                              hipStream_t stream) {
    const float* hA = (const float*)d_in[0];
    const float* hB = (const float*)d_in[1];
    const float* W0 = (const float*)d_in[2];
    const float* b0 = (const float*)d_in[3];
    const float* W1 = (const float*)d_in[4];
    const float* b1 = (const float*)d_in[5];
    const float* W2 = (const float*)d_in[6];
    const float* b2 = (const float*)d_in[7];
    const int* s0 = (const int*)d_in[8];
    const int* d0 = (const int*)d_in[9];
    const int* s1 = (const int*)d_in[10];
    const int* d1 = (const int*)d_in[11];
    const int* s2 = (const int*)d_in[12];
    const int* d2 = (const int*)d_in[13];
    float* out = (float*)d_out;
    char* ws = (char*)d_ws;

    // ws layout: R1-proven offsets; csr shrunk to u16 in place.
    // P16 (10.88 MB packed) aliases mA0 (dead before work_kernel's gemm).
    unsigned short* mA0 = (unsigned short*)(ws + 0);          // 12.8 MB
    unsigned short* mA1 = (unsigned short*)(ws + 12800000);   // 12.8 MB
    unsigned short* mB2 = (unsigned short*)(ws + 25600000);   // 5.12 MB
    unsigned short* P16 = (unsigned short*)(ws + 0);          // 10.88 MB packed counts
    unsigned int*   Pd  = (unsigned int*)(ws + 0);            // dword view of P16
    unsigned short* Wt  = (unsigned short*)(ws + 30720000);   // 96 KB
    float* rdeg         = (float*)(ws + 30818304);            // 960 KB
    int*   ideg         = (int*)  (ws + 31778304);            // 960 KB
    int*   rp           = (int*)  (ws + 32738304);            // 480 KB
    int*   spart        = (int*)  (ws + 33218304);            // 3 KB
    unsigned char* cum8 = (unsigned char*)(ws + 33221376);    // 2.72 MB
    unsigned char* rank0= (unsigned char*)(ws + 35941376);    // 600 KB
    unsigned char* rank1= (unsigned char*)(ws + 36541376);    // 300 KB
    unsigned char* rank2= (unsigned char*)(ws + 36841376);    // 300 KB
    unsigned short* csr0= (unsigned short*)(ws + 37141376);   // 1.2 MB (u16)
    unsigned short* csr1= (unsigned short*)(ws + 38341376);   // 0.6 MB (u16)
    unsigned short* csr2= (unsigned short*)(ws + 38941376);   // 0.6 MB (u16)

    hist_kernel<<<dim3(2, 32, 7), 1024, 0, stream>>>(s0, d0, s1, d1, s2, d2,
        Pd, rank0, rank1, rank2, W0, W1, W2, Wt);
    reduce2<<<dim3(196, 6), 256, 0, stream>>>(P16, ideg, rdeg, spart, cum8);
    scan3<<<dim3(49, 3), 256, 0, stream>>>(ideg, spart, rp);
    work_kernel<<<548 + 587, 512, 0, stream>>>(s0, d0, s1, d1, s2, d2,
        cum8, rank0, rank1, rank2, rp, csr0, csr1, csr2,
        hA, hB, Wt, rdeg, mA0, mA1, mB2);
    gather_all<<<12500 + 5000, 256, 0, stream>>>(mA0, mA1, mB2,
        csr0, csr1, csr2, rp, ideg, rdeg, b0, b1, b2, out);
}

// Round 8
// 239.209 us; speedup vs baseline: 1.3835x; 1.0012x over previous
//
#include <hip/hip_runtime.h>

#define NA 50000
#define NB 20000
#define NE0 600000
#define NE1 300000
#define NE2 300000
#define DD 128
#define SUB 32768     // keys per LDS histogram pass (16-bit packed counters, 64 KB)
#define PER 18750     // edges per group: NE0/32 = NE1/16 = NE2/16

// P packed-ushort cell layout (cell = Po[cfg] + g*K + k):
// cfg0 dout0 G=32,K=NA @0        ; cfg1 din0 G=32,K=NA @1600000
// cfg2 dout1 G=16,K=NA @3200000  ; cfg3 din1 G=16,K=NB @4000000
// cfg4 dout2 G=16,K=NB @4320000  ; cfg5 din2 G=16,K=NA @4640000
// CUM8 uchar layout: C0 @0 (32*NA) ; C1 @1600000 (16*NB) ; C2 @1920000 (16*NA)

typedef short bf16x8 __attribute__((ext_vector_type(8)));
typedef float f32x4 __attribute__((ext_vector_type(4)));

__device__ __forceinline__ unsigned short f2bf(float f) {
    union { float f; unsigned int u; } v; v.f = f;
    unsigned int r = v.u + 0x7fffu + ((v.u >> 16) & 1u);   // RNE
    return (unsigned short)(r >> 16);
}
__device__ __forceinline__ float lo2f(unsigned int u) {
    union { float f; unsigned int u; } v; v.u = u << 16;
    return v.f;
}
__device__ __forceinline__ float hi2f(unsigned int u) {
    union { float f; unsigned int u; } v; v.u = u & 0xffff0000u;
    return v.f;
}

// ---- LDS histograms (z=0..5) + W->bf16 W^T transpose (z=6) ------------------
__global__ __launch_bounds__(1024) void hist_kernel(
    const int* __restrict__ s0, const int* __restrict__ d0,
    const int* __restrict__ s1, const int* __restrict__ d1,
    const int* __restrict__ s2, const int* __restrict__ d2,
    unsigned int* __restrict__ Pd,
    unsigned char* __restrict__ rank0, unsigned char* __restrict__ rank1,
    unsigned char* __restrict__ rank2,
    const float* __restrict__ W0, const float* __restrict__ W1,
    const float* __restrict__ W2, unsigned short* __restrict__ Wt)
{
    __shared__ unsigned int h32[SUB / 2];
    const int cfg = blockIdx.z;
    if (cfg == 6) {   // Wt[w][c*128+k] = bf16(W_w[k*128+c])
        int flat = blockIdx.y * 2 + blockIdx.x;
        if (flat >= 48) return;
        int i = flat * 1024 + threadIdx.x;
        int w = i >> 14, r = i & (DD * DD - 1);
        int c = r >> 7, k = r & (DD - 1);
        const float* W = (w == 0) ? W0 : ((w == 1) ? W1 : W2);
        Wt[i] = f2bf(W[k * DD + c]);
        return;
    }
    const int En[6] = {NE0, NE0, NE1, NE1, NE2, NE2};
    const int Kn[6] = {NA, NA, NA, NB, NB, NA};
    const int Gn[6] = {32, 32, 16, 16, 16, 16};
    const int Po[6] = {0, 1600000, 3200000, 4000000, 4320000, 4640000};
    int E = En[cfg], K = Kn[cfg], G = Gn[cfg];
    int sub = blockIdx.x, g = blockIdx.y;
    int nsub = (K + SUB - 1) / SUB;
    if (sub >= nsub || g >= G) return;
    const int* keys = cfg == 0 ? s0 : cfg == 1 ? d0 : cfg == 2 ? s1
                    : cfg == 3 ? d1 : cfg == 4 ? s2 : d2;
    unsigned char* rk = cfg == 1 ? rank0 : cfg == 3 ? rank1
                      : cfg == 5 ? rank2 : (unsigned char*)0;
    int lo = sub * SUB;
    int hi = min(K, lo + SUB);
    int cnt = hi - lo;
    for (int i = threadIdx.x; i < SUB / 2; i += 1024) h32[i] = 0;
    __syncthreads();
    int e1 = min(E, g * PER + PER);
    for (int e = g * PER + threadIdx.x; e < e1; e += 1024) {
        int k = keys[e];
        if (k >= lo && k < hi) {
            int kk = k - lo;
            unsigned sh = (kk & 1) << 4;
            unsigned old = atomicAdd(&h32[kk >> 1], 1u << sh);
            if (rk) rk[e] = (unsigned char)((old >> sh) & 0xffu);
        }
    }
    __syncthreads();
    unsigned int* outp = Pd + ((Po[cfg] + g * K + lo) >> 1);
    for (int i = threadIdx.x; i < cnt / 2; i += 1024) outp[i] = h32[i];
}

// ---- fused: partial sums -> ideg/rdeg; din cfgs also emit CUM8 + spart ------
// 1 key per thread, fully coalesced. spart granularity: 256-key chunks.
__global__ __launch_bounds__(256) void reduce2(
    const unsigned short* __restrict__ P16, int* __restrict__ ideg,
    float* __restrict__ rdeg, int* __restrict__ spart,
    unsigned char* __restrict__ cum8)
{
    __shared__ int lds[256];
    const int y = blockIdx.y;
    const int Ro[6] = {0, NA, 2 * NA, 3 * NA, 3 * NA + NB, 3 * NA + 2 * NB};
    const int Kr[6] = {NA, NA, NA, NB, NB, NA};
    const int Gr[6] = {32, 32, 16, 16, 16, 16};
    const int Po[6] = {0, 1600000, 3200000, 4000000, 4320000, 4640000};
    const int Co[6] = {0, 0, 0, 1600000, 0, 1920000};
    int K = Kr[y], G = Gr[y];
    int b = blockIdx.x, t = threadIdx.x;
    int nchunk = (K + 255) >> 8;
    if (b >= nchunk) return;
    int key = b * 256 + t;
    bool valid = key < K;
    bool din = (y == 1) || (y == 3) || (y == 5);
    const unsigned short* p = P16 + Po[y] + key;
    unsigned char* cb = cum8 + Co[y] + key;
    int run = 0;
    for (int g = 0; g < G; ++g) {
        if (din && valid) cb[g * K] = (unsigned char)run;
        run += valid ? p[g * K] : 0;
    }
    if (valid) {
        ideg[Ro[y] + key] = run;
        rdeg[Ro[y] + key] = rsqrtf(fmaxf((float)run, 1.f));
    }
    if (din) {
        int slot = (y - 1) >> 1;
        lds[t] = run; __syncthreads();
        for (int o = 128; o > 0; o >>= 1) {
            if (t < o) lds[t] += lds[t + o];
            __syncthreads();
        }
        if (t == 0) spart[slot * 256 + b] = lds[0];
    }
}

// ---- rowptr scan: spine over 256-key spart chunks + block-local scan --------
__global__ __launch_bounds__(256) void scan3(
    const int* __restrict__ ideg, const int* __restrict__ spart,
    int* __restrict__ rp)
{
    __shared__ int lds[256];
    const int y = blockIdx.y;
    const int off[3] = {NA, 3 * NA, 3 * NA + 2 * NB};
    const int nn[3]  = {NA, NB, NA};
    const int ro[3]  = {0, NA, NA + NB};
    int n = nn[y];
    int b = blockIdx.x, t = threadIdx.x;
    if (b * 1024 >= n) return;

    // base = sum of spart chunks [0, 4b)
    lds[t] = (t < 4 * b) ? spart[y * 256 + t] : 0;
    __syncthreads();
    for (int o = 128; o > 0; o >>= 1) {
        if (t < o) lds[t] += lds[t + o];
        __syncthreads();
    }
    int pv = lds[0];
    __syncthreads();

    const int* deg = ideg + off[y];
    int base = b * 1024 + t * 4;
    int v[4]; int tsum = 0;
    #pragma unroll
    for (int k = 0; k < 4; ++k) {
        v[k] = (base + k < n) ? deg[base + k] : 0;
        tsum += v[k];
    }
    lds[t] = tsum; __syncthreads();
    for (int o = 1; o < 256; o <<= 1) {
        int x = (t >= o) ? lds[t - o] : 0;
        __syncthreads();
        lds[t] += x;
        __syncthreads();
    }
    int run = lds[t] - tsum + pv;
    int* rowptr = rp + ro[y];
    #pragma unroll
    for (int k = 0; k < 4; ++k) {
        if (base + k < n) rowptr[base + k] = run;
        run += v[k];
    }
}

// ---- fused work: MFMA GEMMs FIRST (blocks 0..547), placement after ----------
// GEMM-first keeps streaming/MFMA blocks resident from t=0 (R1: +4.5us).
// placement (R1 addressing, proven): pos = rp[d] + cum8[g*K+d] + rank8[e].
// THIS ROUND (single variable): m* output stores are NONTEMPORAL (evict-first).
// They are write-once, never re-read in this kernel, and don't fit L2 anyway;
// freeing that L2 pressure lets csr scatter lines accumulate their ~16 stores
// before writeback (R7: 55MB churn). Loads remain cached (R2 showed nt LOADS
// are what regressed).
__global__ __launch_bounds__(512) void work_kernel(
    const int* __restrict__ s0, const int* __restrict__ d0,
    const int* __restrict__ s1, const int* __restrict__ d1,
    const int* __restrict__ s2, const int* __restrict__ d2,
    const unsigned char* __restrict__ cum8,
    const unsigned char* __restrict__ rank0, const unsigned char* __restrict__ rank1,
    const unsigned char* __restrict__ rank2,
    const int* __restrict__ rp,
    unsigned short* __restrict__ csr0, unsigned short* __restrict__ csr1,
    unsigned short* __restrict__ csr2,
    const float* __restrict__ hA, const float* __restrict__ hB,
    const unsigned short* __restrict__ Wt, const float* __restrict__ rdeg,
    unsigned short* __restrict__ mA0, unsigned short* __restrict__ mA1,
    unsigned short* __restrict__ mB2)
{
    int bx = blockIdx.x;
    int wid  = threadIdx.x >> 6;
    int lane = threadIdx.x & 63;
    int quad = lane >> 4;
    int l16  = lane & 15;
    if (bx < 391) {   // ---- dual-W GEMM over hA ----
        int base = bx * 128 + wid * 16;
        if (base >= NA) return;
        int arow = base + l16;
        if (arow >= NA) arow = NA - 1;
        bf16x8 a[4];
        #pragma unroll
        for (int kk = 0; kk < 4; ++kk) {
            const float4* p = (const float4*)(hA + (size_t)arow * DD + kk * 32 + quad * 8);
            float4 u = p[0], w = p[1];
            bf16x8 t;
            t[0] = (short)f2bf(u.x); t[1] = (short)f2bf(u.y);
            t[2] = (short)f2bf(u.z); t[3] = (short)f2bf(u.w);
            t[4] = (short)f2bf(w.x); t[5] = (short)f2bf(w.y);
            t[6] = (short)f2bf(w.z); t[7] = (short)f2bf(w.w);
            a[kk] = t;
        }
        float rs0[4], rs1[4]; int orow0 = base + quad * 4;
        #pragma unroll
        for (int r = 0; r < 4; ++r) {
            int orow = orow0 + r; int c = orow < NA ? orow : 0;
            rs0[r] = rdeg[c]; rs1[r] = rdeg[2 * NA + c];
        }
        #pragma unroll
        for (int ct = 0; ct < 8; ++ct) {
            f32x4 acc0 = {0.f, 0.f, 0.f, 0.f};
            f32x4 acc1 = {0.f, 0.f, 0.f, 0.f};
            const unsigned short* wp = Wt + (size_t)(ct * 16 + l16) * DD + quad * 8;
            #pragma unroll
            for (int kk = 0; kk < 4; ++kk) {
                bf16x8 b0 = *(const bf16x8*)(wp + kk * 32);
                bf16x8 b1 = *(const bf16x8*)(wp + 16384 + kk * 32);
                acc0 = __builtin_amdgcn_mfma_f32_16x16x32_bf16(a[kk], b0, acc0, 0, 0, 0);
                acc1 = __builtin_amdgcn_mfma_f32_16x16x32_bf16(a[kk], b1, acc1, 0, 0, 0);
            }
            #pragma unroll
            for (int r = 0; r < 4; ++r) {
                int orow = orow0 + r;
                if (orow < NA) {
                    __builtin_nontemporal_store(f2bf(acc0[r] * rs0[r]),
                        &mA0[(size_t)orow * DD + ct * 16 + l16]);
                    __builtin_nontemporal_store(f2bf(acc1[r] * rs1[r]),
                        &mA1[(size_t)orow * DD + ct * 16 + l16]);
                }
            }
        }
        return;
    }
    if (bx < 548) {   // ---- W2 GEMM over hB ----
        int base = (bx - 391) * 128 + wid * 16;
        if (base >= NB) return;
        int arow = base + l16;
        if (arow >= NB) arow = NB - 1;
        bf16x8 a[4];
        #pragma unroll
        for (int kk = 0; kk < 4; ++kk) {
            const float4* p = (const float4*)(hB + (size_t)arow * DD + kk * 32 + quad * 8);
            float4 u = p[0], w = p[1];
            bf16x8 t;
            t[0] = (short)f2bf(u.x); t[1] = (short)f2bf(u.y);
            t[2] = (short)f2bf(u.z); t[3] = (short)f2bf(u.w);
            t[4] = (short)f2bf(w.x); t[5] = (short)f2bf(w.y);
            t[6] = (short)f2bf(w.z); t[7] = (short)f2bf(w.w);
            a[kk] = t;
        }
        float rs[4]; int orow0 = base + quad * 4;
        #pragma unroll
        for (int r = 0; r < 4; ++r) {
            int orow = orow0 + r;
            rs[r] = rdeg[3 * NA + NB + (orow < NB ? orow : 0)];
        }
        #pragma unroll
        for (int ct = 0; ct < 8; ++ct) {
            f32x4 acc = {0.f, 0.f, 0.f, 0.f};
            const unsigned short* wp = Wt + 32768 + (size_t)(ct * 16 + l16) * DD + quad * 8;
            #pragma unroll
            for (int kk = 0; kk < 4; ++kk) {
                bf16x8 b = *(const bf16x8*)(wp + kk * 32);
                acc = __builtin_amdgcn_mfma_f32_16x16x32_bf16(a[kk], b, acc, 0, 0, 0);
            }
            #pragma unroll
            for (int r = 0; r < 4; ++r) {
                int orow = orow0 + r;
                if (orow < NB)
                    __builtin_nontemporal_store(f2bf(acc[r] * rs[r]),
                        &mB2[(size_t)orow * DD + ct * 16 + l16]);
            }
        }
        return;
    }
    // ---- placement: 587 blocks x 2048 edges (4 per thread, independent) ----
    int pb = bx - 548;
    int z = (pb < 293) ? 0 : (pb < 440) ? 1 : 2;
    const int zb[3] = {0, 293, 440};
    const int En[3] = {NE0, NE1, NE2};
    const int Kn[3] = {NA, NB, NA};
    const int Co[3] = {0, 1600000, 1920000};
    const int ro[3] = {0, NA, NA + NB};
    int E = En[z], K = Kn[z];
    const int* src = z == 0 ? s0 : z == 1 ? s1 : s2;
    const int* dst = z == 0 ? d0 : z == 1 ? d1 : d2;
    const unsigned char* rk = z == 0 ? rank0 : z == 1 ? rank1 : rank2;
    unsigned short* csr = z == 0 ? csr0 : z == 1 ? csr1 : csr2;
    int ebase = (pb - zb[z]) * 2048 + threadIdx.x;
    int ce[4]; bool vv[4];
    #pragma unroll
    for (int j = 0; j < 4; ++j) {
        int e = ebase + j * 512;
        vv[j] = e < E;
        ce[j] = vv[j] ? e : 0;
    }
    int dd_[4], rr[4], ss[4];
    #pragma unroll
    for (int j = 0; j < 4; ++j) dd_[j] = dst[ce[j]];   // coalesced
    #pragma unroll
    for (int j = 0; j < 4; ++j) rr[j] = rk[ce[j]];     // coalesced
    #pragma unroll
    for (int j = 0; j < 4; ++j) ss[j] = src[ce[j]];    // coalesced
    int pp[4];
    #pragma unroll
    for (int j = 0; j < 4; ++j) {       // 8 independent random loads in flight
        int g = ce[j] / PER;
        pp[j] = rp[ro[z] + dd_[j]] + (int)cum8[Co[z] + g * K + dd_[j]] + rr[j];
    }
    #pragma unroll
    for (int j = 0; j < 4; ++j)
        if (vv[j]) csr[pp[j]] = (unsigned short)ss[j];
}

// ---- gather: uint4 loads, 16 lanes/row -> 4 edges per wave instruction ------
__device__ __forceinline__ void acc8(float* o, uint4 u) {
    o[0] += lo2f(u.x); o[1] += hi2f(u.x);
    o[2] += lo2f(u.y); o[3] += hi2f(u.y);
    o[4] += lo2f(u.z); o[5] += hi2f(u.z);
    o[6] += lo2f(u.w); o[7] += hi2f(u.w);
}
__device__ __forceinline__ void gather_rel4(
    const char* __restrict__ Mb, const unsigned short* __restrict__ csr,
    int st, int n, int lane, int q, unsigned laneoff, float* o)
{
    for (int ch = 0; ch < n; ch += 64) {
        int m = n - ch; if (m > 64) m = 64;
        int idx = csr[st + ch + (lane < m ? lane : m - 1)];  // coalesced prefetch
        int j = 0;
        for (; j + 8 <= m; j += 8) {        // 2 loads in flight, 8 edges/iter
            int sA = __shfl(idx, j + q);
            int sB = __shfl(idx, j + 4 + q);
            uint4 uA = *(const uint4*)(Mb + (((unsigned)sA << 8) + laneoff));
            uint4 uB = *(const uint4*)(Mb + (((unsigned)sB << 8) + laneoff));
            acc8(o, uA); acc8(o, uB);
        }
        if (j + 4 <= m) {
            int s = __shfl(idx, j + q);
            uint4 u = *(const uint4*)(Mb + (((unsigned)s << 8) + laneoff));
            acc8(o, u);
            j += 4;
        }
        if (j < m) {                        // masked tail group
            int jj = j + q;
            float w = jj < m ? 1.f : 0.f;
            int s = __shfl(idx, jj < m ? jj : m - 1);
            uint4 u = *(const uint4*)(Mb + (((unsigned)s << 8) + laneoff));
            o[0] = fmaf(w, lo2f(u.x), o[0]); o[1] = fmaf(w, hi2f(u.x), o[1]);
            o[2] = fmaf(w, lo2f(u.y), o[2]); o[3] = fmaf(w, hi2f(u.y), o[3]);
            o[4] = fmaf(w, lo2f(u.z), o[4]); o[5] = fmaf(w, hi2f(u.z), o[5]);
            o[6] = fmaf(w, lo2f(u.w), o[6]); o[7] = fmaf(w, hi2f(u.w), o[7]);
        }
    }
}

// ---- fused gather: blocks [0,12500) -> out_A rows; [12500,17500) -> out_B ---
__global__ __launch_bounds__(256) void gather_all(
    const unsigned short* __restrict__ mA0, const unsigned short* __restrict__ mA1,
    const unsigned short* __restrict__ mB2,
    const unsigned short* __restrict__ csr0, const unsigned short* __restrict__ csr1,
    const unsigned short* __restrict__ csr2,
    const int* __restrict__ rp, const int* __restrict__ ideg,
    const float* __restrict__ rdeg,
    const float* __restrict__ b0, const float* __restrict__ b1,
    const float* __restrict__ b2,
    float* __restrict__ out)
{
    int wid = threadIdx.x >> 6, lane = threadIdx.x & 63;
    int q = lane >> 4, l16 = lane & 15;
    unsigned laneoff = (unsigned)l16 * 16u;
    float v[8];
    #pragma unroll
    for (int i = 0; i < 8; ++i) v[i] = 0.f;
    float* op;
    const float *bia, *bib;

    if (blockIdx.x < 12500) {
        int d = blockIdx.x * 4 + wid;   // always < NA
        float c[8];
        #pragma unroll
        for (int i = 0; i < 8; ++i) c[i] = 0.f;
        gather_rel4((const char*)mA0, csr0, rp[d], ideg[NA + d], lane, q, laneoff, v);
        gather_rel4((const char*)mB2, csr2, rp[NA + NB + d], ideg[3 * NA + 2 * NB + d],
                    lane, q, laneoff, c);
        float r0 = rdeg[NA + d], r2 = rdeg[3 * NA + 2 * NB + d];
        #pragma unroll
        for (int i = 0; i < 8; ++i) v[i] = v[i] * r0 + c[i] * r2;
        op = out + (size_t)d * DD;
        bia = b0; bib = b2;
    } else {
        int d = (blockIdx.x - 12500) * 4 + wid;   // always < NB
        gather_rel4((const char*)mA1, csr1, rp[NA + d], ideg[3 * NA + d],
                    lane, q, laneoff, v);
        float r1 = rdeg[3 * NA + d];
        #pragma unroll
        for (int i = 0; i < 8; ++i) v[i] *= r1;
        op = out + (size_t)(NA + d) * DD;
        bia = b1; bib = 0;
    }

    #pragma unroll
    for (int i = 0; i < 8; ++i) {
        v[i] += __shfl_down(v[i], 32);
        v[i] += __shfl_down(v[i], 16);
    }
    if (lane < 16) {
        int col = l16 * 8;
        float4 ba0 = *(const float4*)(bia + col);
        float4 ba1 = *(const float4*)(bia + col + 4);
        if (bib) {
            float4 bb0 = *(const float4*)(bib + col);
            float4 bb1 = *(const float4*)(bib + col + 4);
            ba0.x += bb0.x; ba0.y += bb0.y; ba0.z += bb0.z; ba0.w += bb0.w;
            ba1.x += bb1.x; ba1.y += bb1.y; ba1.z += bb1.z; ba1.w += bb1.w;
        }
        float4 o0 = {v[0] + ba0.x, v[1] + ba0.y, v[2] + ba0.z, v[3] + ba0.w};
        float4 o1 = {v[4] + ba1.x, v[5] + ba1.y, v[6] + ba1.z, v[7] + ba1.w};
        *(float4*)(op + col) = o0;
        *(float4*)(op + col + 4) = o1;
    }
}

extern "C" void kernel_launch(void* const* d_in, const int* in_sizes, int n_in,
                              void* d_out, int out_size, void* d_ws, size_t ws_size,
                              hipStream_t stream) {
    const float* hA = (const float*)d_in[0];
    const float* hB = (const float*)d_in[1];
    const float* W0 = (const float*)d_in[2];
    const float* b0 = (const float*)d_in[3];
    const float* W1 = (const float*)d_in[4];
    const float* b1 = (const float*)d_in[5];
    const float* W2 = (const float*)d_in[6];
    const float* b2 = (const float*)d_in[7];
    const int* s0 = (const int*)d_in[8];
    const int* d0 = (const int*)d_in[9];
    const int* s1 = (const int*)d_in[10];
    const int* d1 = (const int*)d_in[11];
    const int* s2 = (const int*)d_in[12];
    const int* d2 = (const int*)d_in[13];
    float* out = (float*)d_out;
    char* ws = (char*)d_ws;

    // ws layout: R1-proven offsets; csr u16 in place.
    // P16 (10.88 MB packed) aliases mA0 (dead before work_kernel's gemm).
    unsigned short* mA0 = (unsigned short*)(ws + 0);          // 12.8 MB
    unsigned short* mA1 = (unsigned short*)(ws + 12800000);   // 12.8 MB
    unsigned short* mB2 = (unsigned short*)(ws + 25600000);   // 5.12 MB
    unsigned short* P16 = (unsigned short*)(ws + 0);          // 10.88 MB packed counts
    unsigned int*   Pd  = (unsigned int*)(ws + 0);            // dword view of P16
    unsigned short* Wt  = (unsigned short*)(ws + 30720000);   // 96 KB
    float* rdeg         = (float*)(ws + 30818304);            // 960 KB
    int*   ideg         = (int*)  (ws + 31778304);            // 960 KB
    int*   rp           = (int*)  (ws + 32738304);            // 480 KB
    int*   spart        = (int*)  (ws + 33218304);            // 3 KB
    unsigned char* cum8 = (unsigned char*)(ws + 33221376);    // 2.72 MB
    unsigned char* rank0= (unsigned char*)(ws + 35941376);    // 600 KB
    unsigned char* rank1= (unsigned char*)(ws + 36541376);    // 300 KB
    unsigned char* rank2= (unsigned char*)(ws + 36841376);    // 300 KB
    unsigned short* csr0= (unsigned short*)(ws + 37141376);   // 1.2 MB (u16)
    unsigned short* csr1= (unsigned short*)(ws + 38341376);   // 0.6 MB (u16)
    unsigned short* csr2= (unsigned short*)(ws + 38941376);   // 0.6 MB (u16)

    hist_kernel<<<dim3(2, 32, 7), 1024, 0, stream>>>(s0, d0, s1, d1, s2, d2,
        Pd, rank0, rank1, rank2, W0, W1, W2, Wt);
    reduce2<<<dim3(196, 6), 256, 0, stream>>>(P16, ideg, rdeg, spart, cum8);
    scan3<<<dim3(49, 3), 256, 0, stream>>>(ideg, spart, rp);
    work_kernel<<<548 + 587, 512, 0, stream>>>(s0, d0, s1, d1, s2, d2,
        cum8, rank0, rank1, rank2, rp, csr0, csr1, csr2,
        hA, hB, Wt, rdeg, mA0, mA1, mB2);
    gather_all<<<12500 + 5000, 256, 0, stream>>>(mA0, mA1, mB2,
        csr0, csr1, csr2, rp, ideg, rdeg, b0, b1, b2, out);
}

// Round 9
// 235.274 us; speedup vs baseline: 1.4067x; 1.0167x over previous
//
#include <hip/hip_runtime.h>

#define NA 50000
#define NB 20000
#define NE0 600000
#define NE1 300000
#define NE2 300000
#define DD 128
#define SUB 32768     // keys per LDS histogram pass (16-bit packed counters, 64 KB)
#define PER 18750     // edges per group: NE0/32 = NE1/16 = NE2/16

// P packed-ushort cell layout (cell = Po[cfg] + g*K + k):
// cfg0 dout0 G=32,K=NA @0        ; cfg1 din0 G=32,K=NA @1600000
// cfg2 dout1 G=16,K=NA @3200000  ; cfg3 din1 G=16,K=NB @4000000
// cfg4 dout2 G=16,K=NB @4320000  ; cfg5 din2 G=16,K=NA @4640000
// CUM8 uchar layout: C0 @0 (32*NA) ; C1 @1600000 (16*NB) ; C2 @1920000 (16*NA)

typedef short bf16x8 __attribute__((ext_vector_type(8)));
typedef float f32x4 __attribute__((ext_vector_type(4)));

__device__ __forceinline__ unsigned short f2bf(float f) {
    union { float f; unsigned int u; } v; v.f = f;
    unsigned int r = v.u + 0x7fffu + ((v.u >> 16) & 1u);   // RNE
    return (unsigned short)(r >> 16);
}
__device__ __forceinline__ float lo2f(unsigned int u) {
    union { float f; unsigned int u; } v; v.u = u << 16;
    return v.f;
}
__device__ __forceinline__ float hi2f(unsigned int u) {
    union { float f; unsigned int u; } v; v.u = u & 0xffff0000u;
    return v.f;
}

// ---- LDS histograms (z=0..5) + W->bf16 W^T transpose (z=6) ------------------
__global__ __launch_bounds__(1024) void hist_kernel(
    const int* __restrict__ s0, const int* __restrict__ d0,
    const int* __restrict__ s1, const int* __restrict__ d1,
    const int* __restrict__ s2, const int* __restrict__ d2,
    unsigned int* __restrict__ Pd,
    unsigned char* __restrict__ rank0, unsigned char* __restrict__ rank1,
    unsigned char* __restrict__ rank2,
    const float* __restrict__ W0, const float* __restrict__ W1,
    const float* __restrict__ W2, unsigned short* __restrict__ Wt)
{
    __shared__ unsigned int h32[SUB / 2];
    const int cfg = blockIdx.z;
    if (cfg == 6) {   // Wt[w][c*128+k] = bf16(W_w[k*128+c])
        int flat = blockIdx.y * 2 + blockIdx.x;
        if (flat >= 48) return;
        int i = flat * 1024 + threadIdx.x;
        int w = i >> 14, r = i & (DD * DD - 1);
        int c = r >> 7, k = r & (DD - 1);
        const float* W = (w == 0) ? W0 : ((w == 1) ? W1 : W2);
        Wt[i] = f2bf(W[k * DD + c]);
        return;
    }
    const int En[6] = {NE0, NE0, NE1, NE1, NE2, NE2};
    const int Kn[6] = {NA, NA, NA, NB, NB, NA};
    const int Gn[6] = {32, 32, 16, 16, 16, 16};
    const int Po[6] = {0, 1600000, 3200000, 4000000, 4320000, 4640000};
    int E = En[cfg], K = Kn[cfg], G = Gn[cfg];
    int sub = blockIdx.x, g = blockIdx.y;
    int nsub = (K + SUB - 1) / SUB;
    if (sub >= nsub || g >= G) return;
    const int* keys = cfg == 0 ? s0 : cfg == 1 ? d0 : cfg == 2 ? s1
                    : cfg == 3 ? d1 : cfg == 4 ? s2 : d2;
    unsigned char* rk = cfg == 1 ? rank0 : cfg == 3 ? rank1
                      : cfg == 5 ? rank2 : (unsigned char*)0;
    int lo = sub * SUB;
    int hi = min(K, lo + SUB);
    int cnt = hi - lo;
    for (int i = threadIdx.x; i < SUB / 2; i += 1024) h32[i] = 0;
    __syncthreads();
    int e1 = min(E, g * PER + PER);
    for (int e = g * PER + threadIdx.x; e < e1; e += 1024) {
        int k = keys[e];
        if (k >= lo && k < hi) {
            int kk = k - lo;
            unsigned sh = (kk & 1) << 4;
            unsigned old = atomicAdd(&h32[kk >> 1], 1u << sh);
            if (rk) rk[e] = (unsigned char)((old >> sh) & 0xffu);
        }
    }
    __syncthreads();
    unsigned int* outp = Pd + ((Po[cfg] + g * K + lo) >> 1);
    for (int i = threadIdx.x; i < cnt / 2; i += 1024) outp[i] = h32[i];
}

// ---- fused: partial sums -> ideg/rdeg; din cfgs also emit CUM8 + spart ------
// 1 key per thread, fully coalesced. spart granularity: 256-key chunks.
__global__ __launch_bounds__(256) void reduce2(
    const unsigned short* __restrict__ P16, int* __restrict__ ideg,
    float* __restrict__ rdeg, int* __restrict__ spart,
    unsigned char* __restrict__ cum8)
{
    __shared__ int lds[256];
    const int y = blockIdx.y;
    const int Ro[6] = {0, NA, 2 * NA, 3 * NA, 3 * NA + NB, 3 * NA + 2 * NB};
    const int Kr[6] = {NA, NA, NA, NB, NB, NA};
    const int Gr[6] = {32, 32, 16, 16, 16, 16};
    const int Po[6] = {0, 1600000, 3200000, 4000000, 4320000, 4640000};
    const int Co[6] = {0, 0, 0, 1600000, 0, 1920000};
    int K = Kr[y], G = Gr[y];
    int b = blockIdx.x, t = threadIdx.x;
    int nchunk = (K + 255) >> 8;
    if (b >= nchunk) return;
    int key = b * 256 + t;
    bool valid = key < K;
    bool din = (y == 1) || (y == 3) || (y == 5);
    const unsigned short* p = P16 + Po[y] + key;
    unsigned char* cb = cum8 + Co[y] + key;
    int run = 0;
    for (int g = 0; g < G; ++g) {
        if (din && valid) cb[g * K] = (unsigned char)run;
        run += valid ? p[g * K] : 0;
    }
    if (valid) {
        ideg[Ro[y] + key] = run;
        rdeg[Ro[y] + key] = rsqrtf(fmaxf((float)run, 1.f));
    }
    if (din) {
        int slot = (y - 1) >> 1;
        lds[t] = run; __syncthreads();
        for (int o = 128; o > 0; o >>= 1) {
            if (t < o) lds[t] += lds[t + o];
            __syncthreads();
        }
        if (t == 0) spart[slot * 256 + b] = lds[0];
    }
}

// ---- rowptr scan: spine over 256-key spart chunks + block-local scan --------
__global__ __launch_bounds__(256) void scan3(
    const int* __restrict__ ideg, const int* __restrict__ spart,
    int* __restrict__ rp)
{
    __shared__ int lds[256];
    const int y = blockIdx.y;
    const int off[3] = {NA, 3 * NA, 3 * NA + 2 * NB};
    const int nn[3]  = {NA, NB, NA};
    const int ro[3]  = {0, NA, NA + NB};
    int n = nn[y];
    int b = blockIdx.x, t = threadIdx.x;
    if (b * 1024 >= n) return;

    // base = sum of spart chunks [0, 4b)
    lds[t] = (t < 4 * b) ? spart[y * 256 + t] : 0;
    __syncthreads();
    for (int o = 128; o > 0; o >>= 1) {
        if (t < o) lds[t] += lds[t + o];
        __syncthreads();
    }
    int pv = lds[0];
    __syncthreads();

    const int* deg = ideg + off[y];
    int base = b * 1024 + t * 4;
    int v[4]; int tsum = 0;
    #pragma unroll
    for (int k = 0; k < 4; ++k) {
        v[k] = (base + k < n) ? deg[base + k] : 0;
        tsum += v[k];
    }
    lds[t] = tsum; __syncthreads();
    for (int o = 1; o < 256; o <<= 1) {
        int x = (t >= o) ? lds[t - o] : 0;
        __syncthreads();
        lds[t] += x;
        __syncthreads();
    }
    int run = lds[t] - tsum + pv;
    int* rowptr = rp + ro[y];
    #pragma unroll
    for (int k = 0; k < 4; ++k) {
        if (base + k < n) rowptr[base + k] = run;
        run += v[k];
    }
}

// ---- fused work: MFMA GEMMs FIRST (blocks 0..547), placement after ----------
// R8-proven: GEMM-first + nt m-stores (WRITE 91->70MB, dur 59.6->57.2).
// placement: pos = rp[d] + cum8[g*K+d] + rank8[e], 4 edges/thread, u16 csr.
__global__ __launch_bounds__(512) void work_kernel(
    const int* __restrict__ s0, const int* __restrict__ d0,
    const int* __restrict__ s1, const int* __restrict__ d1,
    const int* __restrict__ s2, const int* __restrict__ d2,
    const unsigned char* __restrict__ cum8,
    const unsigned char* __restrict__ rank0, const unsigned char* __restrict__ rank1,
    const unsigned char* __restrict__ rank2,
    const int* __restrict__ rp,
    unsigned short* __restrict__ csr0, unsigned short* __restrict__ csr1,
    unsigned short* __restrict__ csr2,
    const float* __restrict__ hA, const float* __restrict__ hB,
    const unsigned short* __restrict__ Wt, const float* __restrict__ rdeg,
    unsigned short* __restrict__ mA0, unsigned short* __restrict__ mA1,
    unsigned short* __restrict__ mB2)
{
    int bx = blockIdx.x;
    int wid  = threadIdx.x >> 6;
    int lane = threadIdx.x & 63;
    int quad = lane >> 4;
    int l16  = lane & 15;
    if (bx < 391) {   // ---- dual-W GEMM over hA ----
        int base = bx * 128 + wid * 16;
        if (base >= NA) return;
        int arow = base + l16;
        if (arow >= NA) arow = NA - 1;
        bf16x8 a[4];
        #pragma unroll
        for (int kk = 0; kk < 4; ++kk) {
            const float4* p = (const float4*)(hA + (size_t)arow * DD + kk * 32 + quad * 8);
            float4 u = p[0], w = p[1];
            bf16x8 t;
            t[0] = (short)f2bf(u.x); t[1] = (short)f2bf(u.y);
            t[2] = (short)f2bf(u.z); t[3] = (short)f2bf(u.w);
            t[4] = (short)f2bf(w.x); t[5] = (short)f2bf(w.y);
            t[6] = (short)f2bf(w.z); t[7] = (short)f2bf(w.w);
            a[kk] = t;
        }
        float rs0[4], rs1[4]; int orow0 = base + quad * 4;
        #pragma unroll
        for (int r = 0; r < 4; ++r) {
            int orow = orow0 + r; int c = orow < NA ? orow : 0;
            rs0[r] = rdeg[c]; rs1[r] = rdeg[2 * NA + c];
        }
        #pragma unroll
        for (int ct = 0; ct < 8; ++ct) {
            f32x4 acc0 = {0.f, 0.f, 0.f, 0.f};
            f32x4 acc1 = {0.f, 0.f, 0.f, 0.f};
            const unsigned short* wp = Wt + (size_t)(ct * 16 + l16) * DD + quad * 8;
            #pragma unroll
            for (int kk = 0; kk < 4; ++kk) {
                bf16x8 b0 = *(const bf16x8*)(wp + kk * 32);
                bf16x8 b1 = *(const bf16x8*)(wp + 16384 + kk * 32);
                acc0 = __builtin_amdgcn_mfma_f32_16x16x32_bf16(a[kk], b0, acc0, 0, 0, 0);
                acc1 = __builtin_amdgcn_mfma_f32_16x16x32_bf16(a[kk], b1, acc1, 0, 0, 0);
            }
            #pragma unroll
            for (int r = 0; r < 4; ++r) {
                int orow = orow0 + r;
                if (orow < NA) {
                    __builtin_nontemporal_store(f2bf(acc0[r] * rs0[r]),
                        &mA0[(size_t)orow * DD + ct * 16 + l16]);
                    __builtin_nontemporal_store(f2bf(acc1[r] * rs1[r]),
                        &mA1[(size_t)orow * DD + ct * 16 + l16]);
                }
            }
        }
        return;
    }
    if (bx < 548) {   // ---- W2 GEMM over hB ----
        int base = (bx - 391) * 128 + wid * 16;
        if (base >= NB) return;
        int arow = base + l16;
        if (arow >= NB) arow = NB - 1;
        bf16x8 a[4];
        #pragma unroll
        for (int kk = 0; kk < 4; ++kk) {
            const float4* p = (const float4*)(hB + (size_t)arow * DD + kk * 32 + quad * 8);
            float4 u = p[0], w = p[1];
            bf16x8 t;
            t[0] = (short)f2bf(u.x); t[1] = (short)f2bf(u.y);
            t[2] = (short)f2bf(u.z); t[3] = (short)f2bf(u.w);
            t[4] = (short)f2bf(w.x); t[5] = (short)f2bf(w.y);
            t[6] = (short)f2bf(w.z); t[7] = (short)f2bf(w.w);
            a[kk] = t;
        }
        float rs[4]; int orow0 = base + quad * 4;
        #pragma unroll
        for (int r = 0; r < 4; ++r) {
            int orow = orow0 + r;
            rs[r] = rdeg[3 * NA + NB + (orow < NB ? orow : 0)];
        }
        #pragma unroll
        for (int ct = 0; ct < 8; ++ct) {
            f32x4 acc = {0.f, 0.f, 0.f, 0.f};
            const unsigned short* wp = Wt + 32768 + (size_t)(ct * 16 + l16) * DD + quad * 8;
            #pragma unroll
            for (int kk = 0; kk < 4; ++kk) {
                bf16x8 b = *(const bf16x8*)(wp + kk * 32);
                acc = __builtin_amdgcn_mfma_f32_16x16x32_bf16(a[kk], b, acc, 0, 0, 0);
            }
            #pragma unroll
            for (int r = 0; r < 4; ++r) {
                int orow = orow0 + r;
                if (orow < NB)
                    __builtin_nontemporal_store(f2bf(acc[r] * rs[r]),
                        &mB2[(size_t)orow * DD + ct * 16 + l16]);
            }
        }
        return;
    }
    // ---- placement: 587 blocks x 2048 edges (4 per thread, independent) ----
    int pb = bx - 548;
    int z = (pb < 293) ? 0 : (pb < 440) ? 1 : 2;
    const int zb[3] = {0, 293, 440};
    const int En[3] = {NE0, NE1, NE2};
    const int Kn[3] = {NA, NB, NA};
    const int Co[3] = {0, 1600000, 1920000};
    const int ro[3] = {0, NA, NA + NB};
    int E = En[z], K = Kn[z];
    const int* src = z == 0 ? s0 : z == 1 ? s1 : s2;
    const int* dst = z == 0 ? d0 : z == 1 ? d1 : d2;
    const unsigned char* rk = z == 0 ? rank0 : z == 1 ? rank1 : rank2;
    unsigned short* csr = z == 0 ? csr0 : z == 1 ? csr1 : csr2;
    int ebase = (pb - zb[z]) * 2048 + threadIdx.x;
    int ce[4]; bool vv[4];
    #pragma unroll
    for (int j = 0; j < 4; ++j) {
        int e = ebase + j * 512;
        vv[j] = e < E;
        ce[j] = vv[j] ? e : 0;
    }
    int dd_[4], rr[4], ss[4];
    #pragma unroll
    for (int j = 0; j < 4; ++j) dd_[j] = dst[ce[j]];   // coalesced
    #pragma unroll
    for (int j = 0; j < 4; ++j) rr[j] = rk[ce[j]];     // coalesced
    #pragma unroll
    for (int j = 0; j < 4; ++j) ss[j] = src[ce[j]];    // coalesced
    int pp[4];
    #pragma unroll
    for (int j = 0; j < 4; ++j) {       // 8 independent random loads in flight
        int g = ce[j] / PER;
        pp[j] = rp[ro[z] + dd_[j]] + (int)cum8[Co[z] + g * K + dd_[j]] + rr[j];
    }
    #pragma unroll
    for (int j = 0; j < 4; ++j)
        if (vv[j]) csr[pp[j]] = (unsigned short)ss[j];
}

// ---- gather primitives ------------------------------------------------------
// Masked 4-edge group: 16 lanes/row, weight 0 for past-end groups. Same VALU
// cost as the unmasked form (fmaf vs add), uniform control flow.
__device__ __forceinline__ uint4 grp_load(
    const char* __restrict__ Mb, int idx, int j, int m, int q, unsigned laneoff,
    float* w)
{
    int jj = j + q;
    *w = (jj < m) ? 1.f : 0.f;
    int s = __shfl(idx, jj < m ? jj : (m - 1));
    return *(const uint4*)(Mb + (((unsigned)s << 8) + laneoff));
}
__device__ __forceinline__ void acc8w(float* o, uint4 u, float w) {
    o[0] = fmaf(w, lo2f(u.x), o[0]); o[1] = fmaf(w, hi2f(u.x), o[1]);
    o[2] = fmaf(w, lo2f(u.y), o[2]); o[3] = fmaf(w, hi2f(u.y), o[3]);
    o[4] = fmaf(w, lo2f(u.z), o[4]); o[5] = fmaf(w, hi2f(u.z), o[5]);
    o[6] = fmaf(w, lo2f(u.w), o[6]); o[7] = fmaf(w, hi2f(u.w), o[7]);
}

// Dual-relation gather (A rows): walks csr0 and csr2 lists SIMULTANEOUSLY so
// up to 4 independent row-loads are in flight (R8: serialized gathers left
// only 2 in flight; avg degree 12/6 means the inner loop barely iterates).
__device__ void gather_dual(
    const char* __restrict__ M0, const unsigned short* __restrict__ c0,
    int st0, int n0,
    const char* __restrict__ M2, const unsigned short* __restrict__ c2,
    int st2, int n2,
    int lane, int q, unsigned laneoff, float* v, float* cc)
{
    int ch0 = 0, ch2 = 0;
    while (ch0 < n0 || ch2 < n2) {
        int m0 = n0 - ch0; m0 = m0 > 64 ? 64 : (m0 < 0 ? 0 : m0);
        int m2 = n2 - ch2; m2 = m2 > 64 ? 64 : (m2 < 0 ? 0 : m2);
        int idx0 = 0, idx2 = 0;
        if (m0 > 0) idx0 = c0[st0 + ch0 + (lane < m0 ? lane : m0 - 1)];
        if (m2 > 0) idx2 = c2[st2 + ch2 + (lane < m2 ? lane : m2 - 1)];
        int j0 = 0, j2 = 0;
        while (j0 < m0 || j2 < m2) {
            bool a0 = j0 < m0, a1 = j0 + 4 < m0;
            bool b0 = j2 < m2, b1 = j2 + 4 < m2;
            uint4 uA0, uA1, uB0, uB1;
            float wA0, wA1, wB0, wB1;
            if (a0) uA0 = grp_load(M0, idx0, j0,     m0, q, laneoff, &wA0);
            if (a1) uA1 = grp_load(M0, idx0, j0 + 4, m0, q, laneoff, &wA1);
            if (b0) uB0 = grp_load(M2, idx2, j2,     m2, q, laneoff, &wB0);
            if (b1) uB1 = grp_load(M2, idx2, j2 + 4, m2, q, laneoff, &wB1);
            if (a0) acc8w(v,  uA0, wA0);
            if (a1) acc8w(v,  uA1, wA1);
            if (b0) acc8w(cc, uB0, wB0);
            if (b1) acc8w(cc, uB1, wB1);
            j0 += 8; j2 += 8;
        }
        ch0 += m0; ch2 += m2;
    }
}

// Single-relation gather (B rows), 4 groups = 16 edges in flight per iter.
__device__ void gather_quad(
    const char* __restrict__ Mb, const unsigned short* __restrict__ csr,
    int st, int n, int lane, int q, unsigned laneoff, float* o)
{
    for (int ch = 0; ch < n; ch += 64) {
        int m = n - ch; if (m > 64) m = 64;
        int idx = csr[st + ch + (lane < m ? lane : m - 1)];
        for (int j = 0; j < m; j += 16) {
            bool g1 = j + 4 < m, g2 = j + 8 < m, g3 = j + 12 < m;
            uint4 u0, u1, u2, u3;
            float w0, w1, w2, w3;
            u0 = grp_load(Mb, idx, j, m, q, laneoff, &w0);
            if (g1) u1 = grp_load(Mb, idx, j + 4,  m, q, laneoff, &w1);
            if (g2) u2 = grp_load(Mb, idx, j + 8,  m, q, laneoff, &w2);
            if (g3) u3 = grp_load(Mb, idx, j + 12, m, q, laneoff, &w3);
            acc8w(o, u0, w0);
            if (g1) acc8w(o, u1, w1);
            if (g2) acc8w(o, u2, w2);
            if (g3) acc8w(o, u3, w3);
        }
    }
}

// ---- fused gather: blocks [0,12500) -> out_A rows; [12500,17500) -> out_B ---
__global__ __launch_bounds__(256) void gather_all(
    const unsigned short* __restrict__ mA0, const unsigned short* __restrict__ mA1,
    const unsigned short* __restrict__ mB2,
    const unsigned short* __restrict__ csr0, const unsigned short* __restrict__ csr1,
    const unsigned short* __restrict__ csr2,
    const int* __restrict__ rp, const int* __restrict__ ideg,
    const float* __restrict__ rdeg,
    const float* __restrict__ b0, const float* __restrict__ b1,
    const float* __restrict__ b2,
    float* __restrict__ out)
{
    int wid = threadIdx.x >> 6, lane = threadIdx.x & 63;
    int q = lane >> 4, l16 = lane & 15;
    unsigned laneoff = (unsigned)l16 * 16u;
    float v[8];
    #pragma unroll
    for (int i = 0; i < 8; ++i) v[i] = 0.f;
    float* op;
    const float *bia, *bib;

    if (blockIdx.x < 12500) {
        int d = blockIdx.x * 4 + wid;   // always < NA
        float c[8];
        #pragma unroll
        for (int i = 0; i < 8; ++i) c[i] = 0.f;
        gather_dual((const char*)mA0, csr0, rp[d], ideg[NA + d],
                    (const char*)mB2, csr2, rp[NA + NB + d],
                    ideg[3 * NA + 2 * NB + d], lane, q, laneoff, v, c);
        float r0 = rdeg[NA + d], r2 = rdeg[3 * NA + 2 * NB + d];
        #pragma unroll
        for (int i = 0; i < 8; ++i) v[i] = v[i] * r0 + c[i] * r2;
        op = out + (size_t)d * DD;
        bia = b0; bib = b2;
    } else {
        int d = (blockIdx.x - 12500) * 4 + wid;   // always < NB
        gather_quad((const char*)mA1, csr1, rp[NA + d], ideg[3 * NA + d],
                    lane, q, laneoff, v);
        float r1 = rdeg[3 * NA + d];
        #pragma unroll
        for (int i = 0; i < 8; ++i) v[i] *= r1;
        op = out + (size_t)(NA + d) * DD;
        bia = b1; bib = 0;
    }

    #pragma unroll
    for (int i = 0; i < 8; ++i) {
        v[i] += __shfl_down(v[i], 32);
        v[i] += __shfl_down(v[i], 16);
    }
    if (lane < 16) {
        int col = l16 * 8;
        float4 ba0 = *(const float4*)(bia + col);
        float4 ba1 = *(const float4*)(bia + col + 4);
        if (bib) {
            float4 bb0 = *(const float4*)(bib + col);
            float4 bb1 = *(const float4*)(bib + col + 4);
            ba0.x += bb0.x; ba0.y += bb0.y; ba0.z += bb0.z; ba0.w += bb0.w;
            ba1.x += bb1.x; ba1.y += bb1.y; ba1.z += bb1.z; ba1.w += bb1.w;
        }
        float4 o0 = {v[0] + ba0.x, v[1] + ba0.y, v[2] + ba0.z, v[3] + ba0.w};
        float4 o1 = {v[4] + ba1.x, v[5] + ba1.y, v[6] + ba1.z, v[7] + ba1.w};
        *(float4*)(op + col) = o0;
        *(float4*)(op + col + 4) = o1;
    }
}

extern "C" void kernel_launch(void* const* d_in, const int* in_sizes, int n_in,
                              void* d_out, int out_size, void* d_ws, size_t ws_size,
                              hipStream_t stream) {
    const float* hA = (const float*)d_in[0];
    const float* hB = (const float*)d_in[1];
    const float* W0 = (const float*)d_in[2];
    const float* b0 = (const float*)d_in[3];
    const float* W1 = (const float*)d_in[4];
    const float* b1 = (const float*)d_in[5];
    const float* W2 = (const float*)d_in[6];
    const float* b2 = (const float*)d_in[7];
    const int* s0 = (const int*)d_in[8];
    const int* d0 = (const int*)d_in[9];
    const int* s1 = (const int*)d_in[10];
    const int* d1 = (const int*)d_in[11];
    const int* s2 = (const int*)d_in[12];
    const int* d2 = (const int*)d_in[13];
    float* out = (float*)d_out;
    char* ws = (char*)d_ws;

    // ws layout: R1-proven offsets; csr u16 in place.
    // P16 (10.88 MB packed) aliases mA0 (dead before work_kernel's gemm).
    unsigned short* mA0 = (unsigned short*)(ws + 0);          // 12.8 MB
    unsigned short* mA1 = (unsigned short*)(ws + 12800000);   // 12.8 MB
    unsigned short* mB2 = (unsigned short*)(ws + 25600000);   // 5.12 MB
    unsigned short* P16 = (unsigned short*)(ws + 0);          // 10.88 MB packed counts
    unsigned int*   Pd  = (unsigned int*)(ws + 0);            // dword view of P16
    unsigned short* Wt  = (unsigned short*)(ws + 30720000);   // 96 KB
    float* rdeg         = (float*)(ws + 30818304);            // 960 KB
    int*   ideg         = (int*)  (ws + 31778304);            // 960 KB
    int*   rp           = (int*)  (ws + 32738304);            // 480 KB
    int*   spart        = (int*)  (ws + 33218304);            // 3 KB
    unsigned char* cum8 = (unsigned char*)(ws + 33221376);    // 2.72 MB
    unsigned char* rank0= (unsigned char*)(ws + 35941376);    // 600 KB
    unsigned char* rank1= (unsigned char*)(ws + 36541376);    // 300 KB
    unsigned char* rank2= (unsigned char*)(ws + 36841376);    // 300 KB
    unsigned short* csr0= (unsigned short*)(ws + 37141376);   // 1.2 MB (u16)
    unsigned short* csr1= (unsigned short*)(ws + 38341376);   // 0.6 MB (u16)
    unsigned short* csr2= (unsigned short*)(ws + 38941376);   // 0.6 MB (u16)

    hist_kernel<<<dim3(2, 32, 7), 1024, 0, stream>>>(s0, d0, s1, d1, s2, d2,
        Pd, rank0, rank1, rank2, W0, W1, W2, Wt);
    reduce2<<<dim3(196, 6), 256, 0, stream>>>(P16, ideg, rdeg, spart, cum8);
    scan3<<<dim3(49, 3), 256, 0, stream>>>(ideg, spart, rp);
    work_kernel<<<548 + 587, 512, 0, stream>>>(s0, d0, s1, d1, s2, d2,
        cum8, rank0, rank1, rank2, rp, csr0, csr1, csr2,
        hA, hB, Wt, rdeg, mA0, mA1, mB2);
    gather_all<<<12500 + 5000, 256, 0, stream>>>(mA0, mA1, mB2,
        csr0, csr1, csr2, rp, ideg, rdeg, b0, b1, b2, out);
}